// Round 16
// baseline (495.304 us; speedup 1.0000x reference)
//
#include <hip/hip_runtime.h>
#include <hip/hip_bf16.h>

typedef __attribute__((ext_vector_type(8))) __bf16 bf16x8;
typedef __attribute__((ext_vector_type(4))) float f32x4;
typedef __attribute__((ext_vector_type(4))) unsigned int u32x4;
typedef unsigned short u16;
typedef unsigned int u32;

#define TOK 8192          // B*N rows
#define C_DIM 1024
#define OUT_SEC 8388608   // elements per output section (x, q, k, v, hidden)

__device__ __forceinline__ u16 f2bf(float f) {
  return __builtin_bit_cast(u16, __float2bfloat16(f));
}

__device__ __forceinline__ int cvt_pk_bf16(float lo, float hi) {
  int r;
  asm("v_cvt_pk_bf16_f32 %0, %1, %2" : "=v"(r) : "v"(lo), "v"(hi));
  return r;
}

__device__ __forceinline__ float max3f(float a, float b, float c) {
  return fmaxf(fmaxf(a, b), c);   // fuses to v_max3_f32
}

__device__ __forceinline__ void gl_lds16(const void* g, void* l) {
  __builtin_amdgcn_global_load_lds(
      (__attribute__((address_space(1))) void*)const_cast<void*>(g),
      (__attribute__((address_space(3))) void*)l, 16, 0, 0);
}

__device__ __forceinline__ float gelu_f(float x) {
  float y = 0.7978845608f * (x + 0.044715f * x * x * x);
  y = fminf(fmaxf(y, -15.f), 15.f);
  float e = __expf(2.0f * y);
  float th = (e - 1.0f) / (e + 1.0f);
  return 0.5f * x * (1.0f + th);
}

// ---------------- fp32 -> bf16 weight conversion ----------------
__global__ __launch_bounds__(256) void cvt_kernel(const float* __restrict__ in,
                                                  u16* __restrict__ out, int n4) {
  int i = blockIdx.x * blockDim.x + threadIdx.x;
  if (i >= n4) return;
  float4 v = reinterpret_cast<const float4*>(in)[i];
  alignas(8) u16 pk[4];
  pk[0] = f2bf(v.x); pk[1] = f2bf(v.y); pk[2] = f2bf(v.z); pk[3] = f2bf(v.w);
  reinterpret_cast<uint2*>(out)[i] = *reinterpret_cast<uint2*>(pk);
}

// ---------------- LayerNorm (one block per row of 1024) ----------------
__global__ __launch_bounds__(256) void ln_kernel(const float* __restrict__ x,
                                                 const float* __restrict__ w,
                                                 const float* __restrict__ b,
                                                 u16* __restrict__ out) {
  const int row = blockIdx.x;
  const int t = threadIdx.x;
  const float* xr = x + (size_t)row * C_DIM;
  float4 v = reinterpret_cast<const float4*>(xr)[t];
  float s = v.x + v.y + v.z + v.w;
  float ss = v.x * v.x + v.y * v.y + v.z * v.z + v.w * v.w;
#pragma unroll
  for (int off = 1; off < 64; off <<= 1) {
    s += __shfl_xor(s, off, 64);
    ss += __shfl_xor(ss, off, 64);
  }
  __shared__ float red[8];
  const int wv = t >> 6;
  if ((t & 63) == 0) { red[wv] = s; red[4 + wv] = ss; }
  __syncthreads();
  s = red[0] + red[1] + red[2] + red[3];
  ss = red[4] + red[5] + red[6] + red[7];
  const float mu = s * (1.0f / C_DIM);
  const float var = ss * (1.0f / C_DIM) - mu * mu;
  const float rstd = rsqrtf(var + 1e-5f);
  float4 w4 = reinterpret_cast<const float4*>(w)[t];
  float4 b4 = reinterpret_cast<const float4*>(b)[t];
  alignas(8) u16 pk[4];
  pk[0] = f2bf((v.x - mu) * rstd * w4.x + b4.x);
  pk[1] = f2bf((v.y - mu) * rstd * w4.y + b4.y);
  pk[2] = f2bf((v.z - mu) * rstd * w4.z + b4.z);
  pk[3] = f2bf((v.w - mu) * rstd * w4.w + b4.w);
  reinterpret_cast<uint2*>(out + (size_t)row * C_DIM)[t] = *reinterpret_cast<uint2*>(pk);
}

// ---------------- V transpose: fp32 [b][n][h*64+d] -> bf16 Vt[bh][d][n] ----------------
__global__ __launch_bounds__(256) void vtrans_kernel(const float* __restrict__ vsrc,
                                                     u16* __restrict__ vt) {
  const int bh = blockIdx.x, nt = blockIdx.y;
  const int b = bh >> 4, h = bh & 15;
  const int t = threadIdx.x;
  __shared__ u16 T[64][65];
#pragma unroll
  for (int p = 0; p < 4; ++p) {
    const int idx = p * 256 + t;
    const int n = idx >> 4, d4 = (idx & 15) * 4;
    float4 x4 = *reinterpret_cast<const float4*>(
        vsrc + (size_t)(b * 1024 + nt * 64 + n) * 1024 + h * 64 + d4);
    T[d4 + 0][n] = f2bf(x4.x);
    T[d4 + 1][n] = f2bf(x4.y);
    T[d4 + 2][n] = f2bf(x4.z);
    T[d4 + 3][n] = f2bf(x4.w);
  }
  __syncthreads();
  const int d = t >> 2, ns = (t & 3) * 16;
  u16* dst = vt + (size_t)bh * 65536 + (size_t)d * 1024 + nt * 64 + ns;
  alignas(16) u16 tmp[16];
#pragma unroll
  for (int i = 0; i < 16; ++i) tmp[i] = T[d][ns + i];
  reinterpret_cast<uint4*>(dst)[0] = reinterpret_cast<uint4*>(tmp)[0];
  reinterpret_cast<uint4*>(dst)[1] = reinterpret_cast<uint4*>(tmp)[1];
}

#define MFMA_T(AF, BF, BASE)                                                \
  _Pragma("unroll") for (int nf = 0; nf < 4; ++nf) {                        \
    _Pragma("unroll") for (int mf = 0; mf < 4; ++mf)                        \
        acc[(BASE) + mf][nf] = __builtin_amdgcn_mfma_f32_16x16x32_bf16(     \
            AF[mf], BF[nf], acc[(BASE) + mf][nf], 0, 0, 0);                 \
  }

// =====================================================================
// gemm8 v3: 256x256, BK=64, dbuf, lgkm-counted superphase pipeline,
// per-XCD row-ownership. FC1 epilogue: LDS repack + full-line NT stores.
// =====================================================================
enum { EPI8_FC1 = 0 };

template <int EPI>
__global__ __launch_bounds__(512, 2) void gemm8(
    const u16* __restrict__ A, const u16* __restrict__ Bw,
    const float* __restrict__ bias,
    float* __restrict__ out, u16* __restrict__ h1, u16* __restrict__ h2,
    int K) {
  extern __shared__ char smem[];
  const int t = threadIdx.x, lane = t & 63, wid = t >> 6;
  const int wm = wid >> 2, wn = wid & 3;

  // per-XCD row ownership: R=32 row tiles, rpx = 4
  const int k8 = blockIdx.x & 7, jj = blockIdx.x >> 3;
  const int brow0 = (k8 * 4 + (jj & 3)) * 256;
  const int bcol0 = (jj >> 2) * 256;

  const int NT = K >> 6;

  f32x4 zero = {0.f, 0.f, 0.f, 0.f};
  f32x4 acc[8][4];
#pragma unroll
  for (int m = 0; m < 8; ++m)
#pragma unroll
    for (int n = 0; n < 4; ++n) acc[m][n] = zero;

  const int src_slot = ((t & 3) ^ ((t >> 3) & 3)) * 8;
  const int srow = t >> 2;
  auto stage = [&](int buf, int mat, int ks, int ktile) {
    const u16* G = mat ? Bw : A;
    const int gr0 = mat ? bcol0 : brow0;
    const int k0 = ktile * 64 + ks * 32 + src_slot;
    char* dst = smem + ((buf << 16) | (mat << 15) | (ks << 14));
#pragma unroll
    for (int i = 0; i < 2; ++i)
      gl_lds16(G + (size_t)(gr0 + i * 128 + srow) * K + k0, dst + i * 8192 + t * 16);
  };

  const int swz16 = (((lane >> 4) ^ ((lane >> 1) & 3)) << 4);
  const int l15 = lane & 15;

  stage(0, 0, 0, 0);
  stage(0, 1, 0, 0);
  stage(0, 0, 1, 0);
  stage(0, 1, 1, 0);
  asm volatile("s_waitcnt vmcnt(4)" ::: "memory");
  __builtin_amdgcn_s_barrier();

  for (int tt = 0; tt < NT; ++tt) {
    char* As_ = smem + ((tt & 1) << 16);
    char* Bs_ = As_ + 32768;
    const int nbuf = (tt & 1) ^ 1;
    const bool pf = (tt + 1 < NT);
    bf16x8 af[4], af2[4], bfr[4];

    auto LDA = [&](bf16x8* dst8, int MH, int KK) {
#pragma unroll
      for (int mf = 0; mf < 4; ++mf)
        dst8[mf] = *reinterpret_cast<const bf16x8*>(
            As_ + KK * 16384 + (wm * 128 + MH * 64 + mf * 16 + l15) * 64 + swz16);
    };
    auto LDB = [&](int KK) {
#pragma unroll
      for (int nf = 0; nf < 4; ++nf)
        bfr[nf] = *reinterpret_cast<const bf16x8*>(
            Bs_ + KK * 16384 + (wn * 64 + nf * 16 + l15) * 64 + swz16);
    };

    // ---- super-phase 0 (kk=0) ----
    LDB(0);
    LDA(af, 0, 0);
    __builtin_amdgcn_sched_barrier(0);
    LDA(af2, 1, 0);
    __builtin_amdgcn_sched_barrier(0);
    if (pf) { stage(nbuf, 0, 0, tt + 1); stage(nbuf, 1, 0, tt + 1); }
    asm volatile("s_waitcnt lgkmcnt(4)" ::: "memory");
    __builtin_amdgcn_sched_barrier(0);
    __builtin_amdgcn_s_setprio(1);
    MFMA_T(af, bfr, 0)
    asm volatile("s_waitcnt lgkmcnt(0)" ::: "memory");
    __builtin_amdgcn_sched_barrier(0);
    MFMA_T(af2, bfr, 4)
    __builtin_amdgcn_s_setprio(0);
    if (pf) {
      asm volatile("s_waitcnt vmcnt(4)" ::: "memory");
    } else {
      asm volatile("s_waitcnt vmcnt(0)" ::: "memory");
    }
    __builtin_amdgcn_s_barrier();

    // ---- super-phase 1 (kk=1) ----
    LDB(1);
    LDA(af, 1, 1);
    __builtin_amdgcn_sched_barrier(0);
    LDA(af2, 0, 1);
    __builtin_amdgcn_sched_barrier(0);
    if (pf) { stage(nbuf, 0, 1, tt + 1); stage(nbuf, 1, 1, tt + 1); }
    asm volatile("s_waitcnt lgkmcnt(4)" ::: "memory");
    __builtin_amdgcn_sched_barrier(0);
    __builtin_amdgcn_s_setprio(1);
    MFMA_T(af, bfr, 4)
    asm volatile("s_waitcnt lgkmcnt(0)" ::: "memory");
    __builtin_amdgcn_sched_barrier(0);
    MFMA_T(af2, bfr, 0)
    __builtin_amdgcn_s_setprio(0);
    if (pf)
      asm volatile("s_waitcnt vmcnt(4)" ::: "memory");
    __builtin_amdgcn_s_barrier();
  }

  // ---- FC1 epilogue: bias+gelu -> LDS (bf16, XOR-swizzled) -> NT stores
  //      8-lane groups store 128B contiguous lines (no RMW amplification).
  const float* bias_c = bias + bcol0;
  for (int half = 0; half < 2; ++half) {
    __syncthreads();
    if (wm == half) {
#pragma unroll
      for (int m = 0; m < 8; ++m)
#pragma unroll
        for (int n = 0; n < 4; ++n) {
          const int lc = wn * 64 + n * 16 + l15;
          const float bb = bias_c[lc];
#pragma unroll
          for (int j = 0; j < 4; ++j) {
            const int lr = m * 16 + (lane >> 4) * 4 + j;
            const int bo = (lr * 512 + lc * 2) ^ ((lr & 7) << 4);
            *reinterpret_cast<u16*>(smem + bo) = f2bf(gelu_f(acc[m][n][j] + bb));
          }
        }
    }
    __syncthreads();
#pragma unroll
    for (int pass = 0; pass < 2; ++pass) {
      const int row = (t >> 3) + pass * 64;
#pragma unroll
      for (int i = 0; i < 4; ++i) {
        const int chunk = (t & 7) + 8 * i;
        const int bo = (row * 512 + chunk * 16) ^ ((row & 7) << 4);
        u32x4 val = *reinterpret_cast<const u32x4*>(smem + bo);
        __builtin_nontemporal_store(
            val, reinterpret_cast<u32x4*>(
                     h1 + (size_t)(brow0 + half * 128 + row) * 4096 + bcol0 + chunk * 8));
      }
    }
  }
}

// =====================================================================
// gemm8n v5 + per-XCD row-ownership (cached stores — R13 behavior):
// BM=128, BN=256, BK=64, triple-buffer depth-2. QKV / PROJ / FC2.
// =====================================================================
enum { EPIN_PROJ = 0, EPIN_FC2 = 1, EPIN_QKV = 2 };

template <int EPI>
__global__ __launch_bounds__(512, 1) void gemm8n(
    const u16* __restrict__ A, const u16* __restrict__ Bw,
    const float* __restrict__ bias, const float* resid,
    float* out, float* out2_f, u16* __restrict__ h1, u16* __restrict__ h2,
    int K) {
  extern __shared__ char smem[];
  const int t = threadIdx.x, lane = t & 63, wid = t >> 6;
  const int wm = wid >> 2, wn = wid & 3;   // 2M x 4N

  // per-XCD row ownership: R=64 row tiles, rpx = 8
  const int k8 = blockIdx.x & 7, jj = blockIdx.x >> 3;
  const int brow0 = (k8 * 8 + (jj & 7)) * 128;
  const int bcol0 = (jj >> 3) * 256;

  const int NT = K >> 6;

  f32x4 zero = {0.f, 0.f, 0.f, 0.f};
  f32x4 acc[4][4];
#pragma unroll
  for (int m = 0; m < 4; ++m)
#pragma unroll
    for (int n = 0; n < 4; ++n) acc[m][n] = zero;

  const int src_slot = ((t & 3) ^ ((t >> 3) & 3)) * 8;
  const int srow = t >> 2;  // 0..127
  auto stage_all = [&](char* dst, int ktile) {
#pragma unroll
    for (int ks = 0; ks < 2; ++ks) {
      const int k0 = ktile * 64 + ks * 32 + src_slot;
      gl_lds16(A + (size_t)(brow0 + srow) * K + k0, dst + ks * 8192 + t * 16);
    }
#pragma unroll
    for (int ks = 0; ks < 2; ++ks) {
      const int k0 = ktile * 64 + ks * 32 + src_slot;
      char* db = dst + 16384 + ks * 16384;
#pragma unroll
      for (int i = 0; i < 2; ++i)
        gl_lds16(Bw + (size_t)(bcol0 + i * 128 + srow) * K + k0, db + i * 8192 + t * 16);
    }
  };  // 6 gl_lds issues

  const int swz16 = (((lane >> 4) ^ ((lane >> 1) & 3)) << 4);
  const int l15 = lane & 15;

  char* bcur = smem;
  char* bnxt = smem + 49152;
  char* bspr = smem + 98304;

  stage_all(bcur, 0);
  stage_all(bnxt, 1);
  asm volatile("s_waitcnt vmcnt(6)" ::: "memory");
  __builtin_amdgcn_s_barrier();

  for (int tt = 0; tt < NT; ++tt) {
    const bool pf2 = (tt + 2 < NT);
    bf16x8 af[4], af2[4], bfr[4], bfr2[4];

    auto LDA = [&](bf16x8* dst8, int KK) {
#pragma unroll
      for (int mf = 0; mf < 4; ++mf)
        dst8[mf] = *reinterpret_cast<const bf16x8*>(
            bcur + KK * 8192 + (wm * 64 + mf * 16 + l15) * 64 + swz16);
    };
    auto LDB = [&](bf16x8* dst8, int KK) {
#pragma unroll
      for (int nf = 0; nf < 4; ++nf)
        dst8[nf] = *reinterpret_cast<const bf16x8*>(
            bcur + 16384 + KK * 16384 + (wn * 64 + nf * 16 + l15) * 64 + swz16);
    };

    LDA(af, 0);
    LDB(bfr, 0);
    __builtin_amdgcn_sched_barrier(0);
    LDA(af2, 1);
    LDB(bfr2, 1);
    __builtin_amdgcn_sched_barrier(0);
    if (pf2) stage_all(bspr, tt + 2);
    asm volatile("s_waitcnt lgkmcnt(8)" ::: "memory");
    __builtin_amdgcn_sched_barrier(0);
    __builtin_amdgcn_s_setprio(1);
    MFMA_T(af, bfr, 0)
    asm volatile("s_waitcnt lgkmcnt(0)" ::: "memory");
    __builtin_amdgcn_sched_barrier(0);
    MFMA_T(af2, bfr2, 0)
    __builtin_amdgcn_s_setprio(0);
    if (pf2) {
      asm volatile("s_waitcnt vmcnt(6)" ::: "memory");
    } else {
      asm volatile("s_waitcnt vmcnt(0)" ::: "memory");
    }
    __builtin_amdgcn_s_barrier();

    char* tmp = bcur;
    bcur = bnxt;
    bnxt = bspr;
    bspr = tmp;
  }

  // ---- epilogue (cached stores) ----
  const int rb = brow0 + wm * 64;
  const int cb = bcol0 + wn * 64;
#pragma unroll
  for (int m = 0; m < 4; ++m) {
#pragma unroll
    for (int n = 0; n < 4; ++n) {
      const int c = cb + n * 16 + l15;
#pragma unroll
      for (int j = 0; j < 4; ++j) {
        const int r = rb + m * 16 + (lane >> 4) * 4 + j;
        float v = acc[m][n][j];
        if constexpr (EPI == EPIN_PROJ) {
          v += bias[c] + resid[(size_t)r * 1024 + c];
          out[(size_t)r * 1024 + c] = v;
        } else if constexpr (EPI == EPIN_FC2) {
          v += bias[c];
          out[(size_t)r * 1024 + c] = v;                                   // hidden_out
          out2_f[(size_t)r * 1024 + c] = resid[(size_t)r * 1024 + c] + v;  // final x
        } else {  // EPIN_QKV
          const int sec = c >> 10, cc = c & 1023;
          out[(size_t)sec * OUT_SEC + (size_t)r * 1024 + cc] = v;
          const size_t boff =
              (((size_t)(r >> 10) * 16 + (cc >> 6)) * 1024 + (r & 1023)) * 64 + (cc & 63);
          // Qb pre-scaled by 0.125 * log2(e) for exp2-based softmax
          if (sec == 0) h1[boff] = f2bf(v * 0.18033688f);
          else if (sec == 1) h2[boff] = f2bf(v);       // Kb
        }
      }
    }
  }
}

// =====================================================================
// attn v4 (unchanged): swapped-operand, QBLK=32/wave, 2-buffer LDS,
// single barrier + distance-1-tile vmcnt(0) per tile, cvt_pk + max3.
// =====================================================================
__global__ __launch_bounds__(256, 4) void attn_kernel(const u16* __restrict__ Qb,
                                                      const u16* __restrict__ Kb,
                                                      const u16* __restrict__ Vtb,
                                                      u16* __restrict__ ao) {
  const int orig = blockIdx.y * gridDim.x + blockIdx.x;  // 0..1023
  const int wid = (orig & 7) * 128 + (orig >> 3);
  const int bh = wid >> 3;
  const int qt = wid & 7;
  const int b = bh >> 4, h = bh & 15;
  const int t = threadIdx.x, lane = t & 63, wv = t >> 6;
  const int l15 = lane & 15, g = lane >> 4;

  __shared__ u16 KV[2][8192];   // per buffer: K [64][64] @0, V [64][64] @8KB (swizzled)

  const int q0 = qt * 128 + wv * 32;
  bf16x8 qfA[2], qfB[2];
#pragma unroll
  for (int c = 0; c < 2; ++c) {
    qfA[c] = *reinterpret_cast<const bf16x8*>(
        Qb + (size_t)bh * 65536 + (size_t)(q0 + l15) * 64 + c * 32 + g * 8);
    qfB[c] = *reinterpret_cast<const bf16x8*>(
        Qb + (size_t)bh * 65536 + (size_t)(q0 + 16 + l15) * 64 + c * 32 + g * 8);
  }

  f32x4 zero = {0.f, 0.f, 0.f, 0.f};
  f32x4 accO0[4], accO1[4];
#pragma unroll
  for (int nb = 0; nb < 4; ++nb) { accO0[nb] = zero; accO1[nb] = zero; }
  float m0 = -1e30f, m1 = -1e30f, lr0 = 0.f, lr1 = 0.f;

  const char* ktile0 = (const char*)(Kb + (size_t)bh * 65536);
  const char* vbase = (const char*)(Vtb + (size_t)bh * 65536);

  auto stage = [&](int buf, int kv0) {
    char* base = (char*)KV[buf];
#pragma unroll
    for (int i = 0; i < 2; ++i) {
      const int o = i * 4096 + t * 16;
      const int row = o >> 7, colb = o & 127;
      const int swz = colb ^ ((row & 7) << 4);
      gl_lds16(ktile0 + (size_t)kv0 * 128 + (size_t)row * 128 + swz, base + o);
      gl_lds16(vbase + (size_t)row * 2048 + (size_t)kv0 * 2 + swz, base + 8192 + o);
    }
  };  // 4 issues

  stage(0, 0);
  int cur = 0;

  const int a0 = (l15 + ((g & 1) << 5)) << 2;
  const int a1 = a0 + 64;
  const bool up = (lane & 32) != 0;

  for (int tile = 0; tile < 16; ++tile) {
    asm volatile("s_waitcnt vmcnt(0)" ::: "memory");
    __builtin_amdgcn_s_barrier();
    if (tile + 1 < 16) stage(cur ^ 1, (tile + 1) * 64);

    const char* kcur = (const char*)KV[cur];
    const char* vcur = kcur + 8192;

    f32x4 s0[4], s1[4];
#pragma unroll
    for (int jb = 0; jb < 4; ++jb) { s0[jb] = zero; s1[jb] = zero; }
#pragma unroll
    for (int jb = 0; jb < 4; ++jb)
#pragma unroll
      for (int c = 0; c < 2; ++c) {
        const int row = jb * 16 + l15;
        const int colb = c * 64 + g * 16;
        bf16x8 kf = *reinterpret_cast<const bf16x8*>(
            kcur + row * 128 + (colb ^ ((row & 7) << 4)));
        s0[jb] = __builtin_amdgcn_mfma_f32_16x16x32_bf16(kf, qfA[c], s0[jb], 0, 0, 0);
        s1[jb] = __builtin_amdgcn_mfma_f32_16x16x32_bf16(kf, qfB[c], s1[jb], 0, 0, 0);
      }

    int w0[4][2], w1[4][2];
    {
      float ta = max3f(s0[0][0], s0[0][1], s0[0][2]);
      float tb = max3f(s0[0][3], s0[1][0], s0[1][1]);
      float tc = max3f(s0[1][2], s0[1][3], s0[2][0]);
      float td = max3f(s0[2][1], s0[2][2], s0[2][3]);
      float te = max3f(s0[3][0], s0[3][1], s0[3][2]);
      float mt = max3f(max3f(ta, tb, tc), max3f(td, te, s0[3][3]), -1e30f);
      mt = fmaxf(mt, __shfl_xor(mt, 16, 64));
      mt = fmaxf(mt, __shfl_xor(mt, 32, 64));
      if (!__all(mt <= m0 + 8.0f)) {
        const float mn = fmaxf(m0, mt);
        const float sc = exp2f(m0 - mn);
        lr0 *= sc;
#pragma unroll
        for (int nb = 0; nb < 4; ++nb) accO0[nb] *= sc;
        m0 = mn;
      }
      float rs = 0.f;
#pragma unroll
      for (int jb = 0; jb < 4; ++jb)
#pragma unroll
        for (int r = 0; r < 4; ++r) {
          const float p = exp2f(s0[jb][r] - m0);
          s0[jb][r] = p;
          rs += p;
        }
      lr0 += rs;
#pragma unroll
      for (int jb = 0; jb < 4; ++jb) {
        w0[jb][0] = cvt_pk_bf16(s0[jb][0], s0[jb][1]);
        w0[jb][1] = cvt_pk_bf16(s0[jb][2], s0[jb][3]);
      }
    }
    {
      float ta = max3f(s1[0][0], s1[0][1], s1[0][2]);
      float tb = max3f(s1[0][3], s1[1][0], s1[1][1]);
      float tc = max3f(s1[1][2], s1[1][3], s1[2][0]);
      float td = max3f(s1[2][1], s1[2][2], s1[2][3]);
      float te = max3f(s1[3][0], s1[3][1], s1[3][2]);
      float mt = max3f(max3f(ta, tb, tc), max3f(td, te, s1[3][3]), -1e30f);
      mt = fmaxf(mt, __shfl_xor(mt, 16, 64));
      mt = fmaxf(mt, __shfl_xor(mt, 32, 64));
      if (!__all(mt <= m1 + 8.0f)) {
        const float mn = fmaxf(m1, mt);
        const float sc = exp2f(m1 - mn);
        lr1 *= sc;
#pragma unroll
        for (int nb = 0; nb < 4; ++nb) accO1[nb] *= sc;
        m1 = mn;
      }
      float rs = 0.f;
#pragma unroll
      for (int jb = 0; jb < 4; ++jb)
#pragma unroll
        for (int r = 0; r < 4; ++r) {
          const float p = exp2f(s1[jb][r] - m1);
          s1[jb][r] = p;
          rs += p;
        }
      lr1 += rs;
#pragma unroll
      for (int jb = 0; jb < 4; ++jb) {
        w1[jb][0] = cvt_pk_bf16(s1[jb][0], s1[jb][1]);
        w1[jb][1] = cvt_pk_bf16(s1[jb][2], s1[jb][3]);
      }
    }

#pragma unroll
    for (int c = 0; c < 2; ++c) {
      int p0w0 = __builtin_amdgcn_ds_bpermute(a0, w0[2 * c][0]);
      int p0w0h = __builtin_amdgcn_ds_bpermute(a0, w0[2 * c + 1][0]);
      int p0w1 = __builtin_amdgcn_ds_bpermute(a0, w0[2 * c][1]);
      int p0w1h = __builtin_amdgcn_ds_bpermute(a0, w0[2 * c + 1][1]);
      int p0w2 = __builtin_amdgcn_ds_bpermute(a1, w0[2 * c][0]);
      int p0w2h = __builtin_amdgcn_ds_bpermute(a1, w0[2 * c + 1][0]);
      int p0w3 = __builtin_amdgcn_ds_bpermute(a1, w0[2 * c][1]);
      int p0w3h = __builtin_amdgcn_ds_bpermute(a1, w0[2 * c + 1][1]);
      alignas(16) int word0[4] = {up ? p0w0h : p0w0, up ? p0w1h : p0w1,
                                  up ? p0w2h : p0w2, up ? p0w3h : p0w3};
      bf16x8 pf0 = *reinterpret_cast<bf16x8*>(word0);

      int p1w0 = __builtin_amdgcn_ds_bpermute(a0, w1[2 * c][0]);
      int p1w0h = __builtin_amdgcn_ds_bpermute(a0, w1[2 * c + 1][0]);
      int p1w1 = __builtin_amdgcn_ds_bpermute(a0, w1[2 * c][1]);
      int p1w1h = __builtin_amdgcn_ds_bpermute(a0, w1[2 * c + 1][1]);
      int p1w2 = __builtin_amdgcn_ds_bpermute(a1, w1[2 * c][0]);
      int p1w2h = __builtin_amdgcn_ds_bpermute(a1, w1[2 * c + 1][0]);
      int p1w3 = __builtin_amdgcn_ds_bpermute(a1, w1[2 * c][1]);
      int p1w3h = __builtin_amdgcn_ds_bpermute(a1, w1[2 * c + 1][1]);
      alignas(16) int word1[4] = {up ? p1w0h : p1w0, up ? p1w1h : p1w1,
                                  up ? p1w2h : p1w2, up ? p1w3h : p1w3};
      bf16x8 pf1 = *reinterpret_cast<bf16x8*>(word1);

#pragma unroll
      for (int nb = 0; nb < 4; ++nb) {
        const int row = nb * 16 + l15;
        const int colb = c * 64 + g * 16;
        bf16x8 vf = *reinterpret_cast<const bf16x8*>(
            vcur + row * 128 + (colb ^ ((row & 7) << 4)));
        accO0[nb] = __builtin_amdgcn_mfma_f32_16x16x32_bf16(vf, pf0, accO0[nb], 0, 0, 0);
        accO1[nb] = __builtin_amdgcn_mfma_f32_16x16x32_bf16(vf, pf1, accO1[nb], 0, 0, 0);
      }
    }

    cur ^= 1;
  }

  lr0 += __shfl_xor(lr0, 16, 64);
  lr0 += __shfl_xor(lr0, 32, 64);
  lr1 += __shfl_xor(lr1, 16, 64);
  lr1 += __shfl_xor(lr1, 32, 64);
  const float rl0 = __builtin_amdgcn_rcpf(lr0);
  const float rl1 = __builtin_amdgcn_rcpf(lr1);

  u16* dst0 = ao + (size_t)(b * 1024 + q0 + l15) * 1024 + h * 64 + g * 4;
  u16* dst1 = ao + (size_t)(b * 1024 + q0 + 16 + l15) * 1024 + h * 64 + g * 4;
#pragma unroll
  for (int nb = 0; nb < 4; ++nb) {
    alignas(8) u16 pk0[4], pk1[4];
#pragma unroll
    for (int j = 0; j < 4; ++j) {
      pk0[j] = f2bf(accO0[nb][j] * rl0);
      pk1[j] = f2bf(accO1[nb][j] * rl1);
    }
    *reinterpret_cast<uint2*>(dst0 + nb * 16) = *reinterpret_cast<uint2*>(pk0);
    *reinterpret_cast<uint2*>(dst1 + nb * 16) = *reinterpret_cast<uint2*>(pk1);
  }
}

// ---------------- launch ----------------
extern "C" void kernel_launch(void* const* d_in, const int* in_sizes, int n_in,
                              void* d_out, int out_size, void* d_ws, size_t ws_size,
                              hipStream_t stream) {
  const float* x      = (const float*)d_in[0];
  const float* n1w    = (const float*)d_in[1];
  const float* n1b    = (const float*)d_in[2];
  const float* qkv_w  = (const float*)d_in[3];
  const float* proj_w = (const float*)d_in[4];
  const float* proj_b = (const float*)d_in[5];
  const float* n2w    = (const float*)d_in[6];
  const float* n2b    = (const float*)d_in[7];
  const float* fc1_w  = (const float*)d_in[8];
  const float* fc1_b  = (const float*)d_in[9];
  const float* fc2_w  = (const float*)d_in[10];
  const float* fc2_b  = (const float*)d_in[11];
  float* out = (float*)d_out;

  // workspace layout (u16 elements)
  u16* wsb    = (u16*)d_ws;
  u16* w_qkv  = wsb;               // 3072*1024
  u16* w_proj = wsb + 3145728;     // 1024*1024
  u16* w_fc1  = wsb + 4194304;     // 4096*1024
  u16* w_fc2  = wsb + 8388608;     // 1024*4096
  u16* xn     = wsb + 12582912;    // 8192*1024 (reused for xn2)
  u16* Qb     = wsb + 20971520;    // 128*1024*64 bf16 (scaled q)
  u16* Kb     = wsb + 29360128;    // 128*1024*64
  u16* Vtw    = wsb + 37748736;    // 128*64*1024
  u16* ao     = wsb + 46137344;    // 8192*1024
  u16* hbuf   = wsb + 20971520;    // 8192*4096, aliases Qb..ao (dead by fc1)

  (void)hipFuncSetAttribute((const void*)gemm8<EPI8_FC1>,
                            hipFuncAttributeMaxDynamicSharedMemorySize, 131072);
  (void)hipFuncSetAttribute((const void*)gemm8n<EPIN_PROJ>,
                            hipFuncAttributeMaxDynamicSharedMemorySize, 147456);
  (void)hipFuncSetAttribute((const void*)gemm8n<EPIN_FC2>,
                            hipFuncAttributeMaxDynamicSharedMemorySize, 147456);
  (void)hipFuncSetAttribute((const void*)gemm8n<EPIN_QKV>,
                            hipFuncAttributeMaxDynamicSharedMemorySize, 147456);

  cvt_kernel<<<3072, 256, 0, stream>>>(qkv_w, w_qkv, 786432);
  cvt_kernel<<<1024, 256, 0, stream>>>(proj_w, w_proj, 262144);
  cvt_kernel<<<4096, 256, 0, stream>>>(fc1_w, w_fc1, 1048576);
  cvt_kernel<<<4096, 256, 0, stream>>>(fc2_w, w_fc2, 1048576);

  ln_kernel<<<TOK, 256, 0, stream>>>(x, n1w, n1b, xn);
  // q,k,v fp32 -> d_out sections 1..3 ; Qb/Kb bf16 (grid 64x12 = 768)
  gemm8n<EPIN_QKV><<<768, 512, 147456, stream>>>(
      xn, w_qkv, nullptr, nullptr, out + OUT_SEC, nullptr, Qb, Kb, 1024);
  vtrans_kernel<<<dim3(128, 16), 256, 0, stream>>>(out + 3 * (size_t)OUT_SEC, Vtw);
  attn_kernel<<<dim3(128, 8), 256, 0, stream>>>(Qb, Kb, Vtw, ao);
  // x_mid = x + ao*proj^T + proj_b (grid 64x4 = 256)
  gemm8n<EPIN_PROJ><<<256, 512, 147456, stream>>>(
      ao, w_proj, proj_b, x, out, nullptr, nullptr, nullptr, 1024);
  ln_kernel<<<TOK, 256, 0, stream>>>(out, n2w, n2b, xn);
  // h = gelu(xn2*fc1^T + fc1_b) (256^2 tile, grid 32x16 = 512)
  gemm8<EPI8_FC1><<<512, 512, 131072, stream>>>(
      xn, w_fc1, fc1_b, nullptr, hbuf, nullptr, 1024);
  // hidden + final x (grid 64x4 = 256)
  gemm8n<EPIN_FC2><<<256, 512, 147456, stream>>>(
      hbuf, w_fc2, fc2_b, out, out + 4 * (size_t)OUT_SEC, out, nullptr, nullptr, 4096);
}

// Round 17
// 385.167 us; speedup vs baseline: 1.2859x; 1.2859x over previous
//
#include <hip/hip_runtime.h>
#include <hip/hip_bf16.h>

typedef __attribute__((ext_vector_type(8))) __bf16 bf16x8;
typedef __attribute__((ext_vector_type(4))) float f32x4;
typedef unsigned short u16;
typedef unsigned int u32;

#define TOK 8192          // B*N rows
#define C_DIM 1024
#define OUT_SEC 8388608   // elements per output section (x, q, k, v, hidden)

__device__ __forceinline__ u16 f2bf(float f) {
  return __builtin_bit_cast(u16, __float2bfloat16(f));
}

__device__ __forceinline__ int cvt_pk_bf16(float lo, float hi) {
  int r;
  asm("v_cvt_pk_bf16_f32 %0, %1, %2" : "=v"(r) : "v"(lo), "v"(hi));
  return r;
}

__device__ __forceinline__ float max3f(float a, float b, float c) {
  return fmaxf(fmaxf(a, b), c);   // fuses to v_max3_f32
}

__device__ __forceinline__ void gl_lds16(const void* g, void* l) {
  __builtin_amdgcn_global_load_lds(
      (__attribute__((address_space(1))) void*)const_cast<void*>(g),
      (__attribute__((address_space(3))) void*)l, 16, 0, 0);
}

__device__ __forceinline__ float gelu_f(float x) {
  float y = 0.7978845608f * (x + 0.044715f * x * x * x);
  y = fminf(fmaxf(y, -15.f), 15.f);
  float e = __expf(2.0f * y);
  float th = (e - 1.0f) / (e + 1.0f);
  return 0.5f * x * (1.0f + th);
}

// ---------------- fp32 -> bf16 weight conversion ----------------
__global__ __launch_bounds__(256) void cvt_kernel(const float* __restrict__ in,
                                                  u16* __restrict__ out, int n4) {
  int i = blockIdx.x * blockDim.x + threadIdx.x;
  if (i >= n4) return;
  float4 v = reinterpret_cast<const float4*>(in)[i];
  alignas(8) u16 pk[4];
  pk[0] = f2bf(v.x); pk[1] = f2bf(v.y); pk[2] = f2bf(v.z); pk[3] = f2bf(v.w);
  reinterpret_cast<uint2*>(out)[i] = *reinterpret_cast<uint2*>(pk);
}

// ---------------- LayerNorm (one block per row of 1024) ----------------
__global__ __launch_bounds__(256) void ln_kernel(const float* __restrict__ x,
                                                 const float* __restrict__ w,
                                                 const float* __restrict__ b,
                                                 u16* __restrict__ out) {
  const int row = blockIdx.x;
  const int t = threadIdx.x;
  const float* xr = x + (size_t)row * C_DIM;
  float4 v = reinterpret_cast<const float4*>(xr)[t];
  float s = v.x + v.y + v.z + v.w;
  float ss = v.x * v.x + v.y * v.y + v.z * v.z + v.w * v.w;
#pragma unroll
  for (int off = 1; off < 64; off <<= 1) {
    s += __shfl_xor(s, off, 64);
    ss += __shfl_xor(ss, off, 64);
  }
  __shared__ float red[8];
  const int wv = t >> 6;
  if ((t & 63) == 0) { red[wv] = s; red[4 + wv] = ss; }
  __syncthreads();
  s = red[0] + red[1] + red[2] + red[3];
  ss = red[4] + red[5] + red[6] + red[7];
  const float mu = s * (1.0f / C_DIM);
  const float var = ss * (1.0f / C_DIM) - mu * mu;
  const float rstd = rsqrtf(var + 1e-5f);
  float4 w4 = reinterpret_cast<const float4*>(w)[t];
  float4 b4 = reinterpret_cast<const float4*>(b)[t];
  alignas(8) u16 pk[4];
  pk[0] = f2bf((v.x - mu) * rstd * w4.x + b4.x);
  pk[1] = f2bf((v.y - mu) * rstd * w4.y + b4.y);
  pk[2] = f2bf((v.z - mu) * rstd * w4.z + b4.z);
  pk[3] = f2bf((v.w - mu) * rstd * w4.w + b4.w);
  reinterpret_cast<uint2*>(out + (size_t)row * C_DIM)[t] = *reinterpret_cast<uint2*>(pk);
}

// ---------------- V transpose: fp32 [b][n][h*64+d] -> bf16 Vt[bh][d][n] ----------------
__global__ __launch_bounds__(256) void vtrans_kernel(const float* __restrict__ vsrc,
                                                     u16* __restrict__ vt) {
  const int bh = blockIdx.x, nt = blockIdx.y;
  const int b = bh >> 4, h = bh & 15;
  const int t = threadIdx.x;
  __shared__ u16 T[64][65];
#pragma unroll
  for (int p = 0; p < 4; ++p) {
    const int idx = p * 256 + t;
    const int n = idx >> 4, d4 = (idx & 15) * 4;
    float4 x4 = *reinterpret_cast<const float4*>(
        vsrc + (size_t)(b * 1024 + nt * 64 + n) * 1024 + h * 64 + d4);
    T[d4 + 0][n] = f2bf(x4.x);
    T[d4 + 1][n] = f2bf(x4.y);
    T[d4 + 2][n] = f2bf(x4.z);
    T[d4 + 3][n] = f2bf(x4.w);
  }
  __syncthreads();
  const int d = t >> 2, ns = (t & 3) * 16;
  u16* dst = vt + (size_t)bh * 65536 + (size_t)d * 1024 + nt * 64 + ns;
  alignas(16) u16 tmp[16];
#pragma unroll
  for (int i = 0; i < 16; ++i) tmp[i] = T[d][ns + i];
  reinterpret_cast<uint4*>(dst)[0] = reinterpret_cast<uint4*>(tmp)[0];
  reinterpret_cast<uint4*>(dst)[1] = reinterpret_cast<uint4*>(tmp)[1];
}

#define MFMA_T(AF, BF, BASE)                                                \
  _Pragma("unroll") for (int nf = 0; nf < 4; ++nf) {                        \
    _Pragma("unroll") for (int mf = 0; mf < 4; ++mf)                        \
        acc[(BASE) + mf][nf] = __builtin_amdgcn_mfma_f32_16x16x32_bf16(     \
            AF[mf], BF[nf], acc[(BASE) + mf][nf], 0, 0, 0);                 \
  }

// =====================================================================
// gemm8 v2 + per-XCD row-ownership mapping (R13 exact): 256x256, BK=64,
// dbuf, lgkm-counted superphase pipeline. FC1 (512 blocks, 32Rx16C):
// XCD k owns row-tiles [4k,4k+4) -> A stripe 2MB L2-resident.
// =====================================================================
enum { EPI8_FC1 = 0 };

template <int EPI>
__global__ __launch_bounds__(512, 2) void gemm8(
    const u16* __restrict__ A, const u16* __restrict__ Bw,
    const float* __restrict__ bias,
    float* __restrict__ out, u16* __restrict__ h1, u16* __restrict__ h2,
    int K) {
  extern __shared__ char smem[];
  const int t = threadIdx.x, lane = t & 63, wid = t >> 6;
  const int wm = wid >> 2, wn = wid & 3;

  // per-XCD row ownership: R=32 row tiles, rpx = 4
  const int k8 = blockIdx.x & 7, jj = blockIdx.x >> 3;
  const int brow0 = (k8 * 4 + (jj & 3)) * 256;
  const int bcol0 = (jj >> 2) * 256;

  const int NT = K >> 6;

  f32x4 zero = {0.f, 0.f, 0.f, 0.f};
  f32x4 acc[8][4];
#pragma unroll
  for (int m = 0; m < 8; ++m)
#pragma unroll
    for (int n = 0; n < 4; ++n) acc[m][n] = zero;

  const int src_slot = ((t & 3) ^ ((t >> 3) & 3)) * 8;
  const int srow = t >> 2;
  auto stage = [&](int buf, int mat, int ks, int ktile) {
    const u16* G = mat ? Bw : A;
    const int gr0 = mat ? bcol0 : brow0;
    const int k0 = ktile * 64 + ks * 32 + src_slot;
    char* dst = smem + ((buf << 16) | (mat << 15) | (ks << 14));
#pragma unroll
    for (int i = 0; i < 2; ++i)
      gl_lds16(G + (size_t)(gr0 + i * 128 + srow) * K + k0, dst + i * 8192 + t * 16);
  };

  const int swz16 = (((lane >> 4) ^ ((lane >> 1) & 3)) << 4);
  const int l15 = lane & 15;

  stage(0, 0, 0, 0);
  stage(0, 1, 0, 0);
  stage(0, 0, 1, 0);
  stage(0, 1, 1, 0);
  asm volatile("s_waitcnt vmcnt(4)" ::: "memory");
  __builtin_amdgcn_s_barrier();

  for (int tt = 0; tt < NT; ++tt) {
    char* As_ = smem + ((tt & 1) << 16);
    char* Bs_ = As_ + 32768;
    const int nbuf = (tt & 1) ^ 1;
    const bool pf = (tt + 1 < NT);
    bf16x8 af[4], af2[4], bfr[4];

    auto LDA = [&](bf16x8* dst8, int MH, int KK) {
#pragma unroll
      for (int mf = 0; mf < 4; ++mf)
        dst8[mf] = *reinterpret_cast<const bf16x8*>(
            As_ + KK * 16384 + (wm * 128 + MH * 64 + mf * 16 + l15) * 64 + swz16);
    };
    auto LDB = [&](int KK) {
#pragma unroll
      for (int nf = 0; nf < 4; ++nf)
        bfr[nf] = *reinterpret_cast<const bf16x8*>(
            Bs_ + KK * 16384 + (wn * 64 + nf * 16 + l15) * 64 + swz16);
    };

    // ---- super-phase 0 (kk=0) ----
    LDB(0);
    LDA(af, 0, 0);
    __builtin_amdgcn_sched_barrier(0);
    LDA(af2, 1, 0);
    __builtin_amdgcn_sched_barrier(0);
    if (pf) { stage(nbuf, 0, 0, tt + 1); stage(nbuf, 1, 0, tt + 1); }
    asm volatile("s_waitcnt lgkmcnt(4)" ::: "memory");
    __builtin_amdgcn_sched_barrier(0);
    __builtin_amdgcn_s_setprio(1);
    MFMA_T(af, bfr, 0)
    asm volatile("s_waitcnt lgkmcnt(0)" ::: "memory");
    __builtin_amdgcn_sched_barrier(0);
    MFMA_T(af2, bfr, 4)
    __builtin_amdgcn_s_setprio(0);
    if (pf) {
      asm volatile("s_waitcnt vmcnt(4)" ::: "memory");
    } else {
      asm volatile("s_waitcnt vmcnt(0)" ::: "memory");
    }
    __builtin_amdgcn_s_barrier();

    // ---- super-phase 1 (kk=1) ----
    LDB(1);
    LDA(af, 1, 1);
    __builtin_amdgcn_sched_barrier(0);
    LDA(af2, 0, 1);
    __builtin_amdgcn_sched_barrier(0);
    if (pf) { stage(nbuf, 0, 1, tt + 1); stage(nbuf, 1, 1, tt + 1); }
    asm volatile("s_waitcnt lgkmcnt(4)" ::: "memory");
    __builtin_amdgcn_sched_barrier(0);
    __builtin_amdgcn_s_setprio(1);
    MFMA_T(af, bfr, 4)
    asm volatile("s_waitcnt lgkmcnt(0)" ::: "memory");
    __builtin_amdgcn_sched_barrier(0);
    MFMA_T(af2, bfr, 0)
    __builtin_amdgcn_s_setprio(0);
    if (pf)
      asm volatile("s_waitcnt vmcnt(4)" ::: "memory");
    __builtin_amdgcn_s_barrier();
  }

  // ---- epilogue (FC1: bias + gelu -> bf16 h, cached stores) ----
  const int rb = brow0 + wm * 128;
  const int cb = bcol0 + wn * 64;
#pragma unroll
  for (int m = 0; m < 8; ++m) {
#pragma unroll
    for (int n = 0; n < 4; ++n) {
      const int c = cb + n * 16 + l15;
#pragma unroll
      for (int j = 0; j < 4; ++j) {
        const int r = rb + m * 16 + (lane >> 4) * 4 + j;
        float v = acc[m][n][j];
        v += bias[c];
        h1[(size_t)r * 4096 + c] = f2bf(gelu_f(v));
      }
    }
  }
}

// =====================================================================
// gemm8n v5 + per-XCD row-ownership mapping (R13 exact): BM=128, BN=256,
// BK=64, triple-buffer depth-2. R=64 row tiles, rpx = 8. QKV/PROJ/FC2.
// =====================================================================
enum { EPIN_PROJ = 0, EPIN_FC2 = 1, EPIN_QKV = 2 };

template <int EPI>
__global__ __launch_bounds__(512, 1) void gemm8n(
    const u16* __restrict__ A, const u16* __restrict__ Bw,
    const float* __restrict__ bias, const float* resid,
    float* out, float* out2_f, u16* __restrict__ h1, u16* __restrict__ h2,
    int K) {
  extern __shared__ char smem[];
  const int t = threadIdx.x, lane = t & 63, wid = t >> 6;
  const int wm = wid >> 2, wn = wid & 3;   // 2M x 4N

  // per-XCD row ownership: R=64 row tiles, rpx = 8
  const int k8 = blockIdx.x & 7, jj = blockIdx.x >> 3;
  const int brow0 = (k8 * 8 + (jj & 7)) * 128;
  const int bcol0 = (jj >> 3) * 256;

  const int NT = K >> 6;

  f32x4 zero = {0.f, 0.f, 0.f, 0.f};
  f32x4 acc[4][4];
#pragma unroll
  for (int m = 0; m < 4; ++m)
#pragma unroll
    for (int n = 0; n < 4; ++n) acc[m][n] = zero;

  const int src_slot = ((t & 3) ^ ((t >> 3) & 3)) * 8;
  const int srow = t >> 2;  // 0..127
  // per-buffer layout (48KB): [Ak0 8K][Ak1 8K][Bk0 16K][Bk1 16K]
  auto stage_all = [&](char* dst, int ktile) {
#pragma unroll
    for (int ks = 0; ks < 2; ++ks) {
      const int k0 = ktile * 64 + ks * 32 + src_slot;
      gl_lds16(A + (size_t)(brow0 + srow) * K + k0, dst + ks * 8192 + t * 16);
    }
#pragma unroll
    for (int ks = 0; ks < 2; ++ks) {
      const int k0 = ktile * 64 + ks * 32 + src_slot;
      char* db = dst + 16384 + ks * 16384;
#pragma unroll
      for (int i = 0; i < 2; ++i)
        gl_lds16(Bw + (size_t)(bcol0 + i * 128 + srow) * K + k0, db + i * 8192 + t * 16);
    }
  };  // 6 gl_lds issues

  const int swz16 = (((lane >> 4) ^ ((lane >> 1) & 3)) << 4);
  const int l15 = lane & 15;

  char* bcur = smem;
  char* bnxt = smem + 49152;
  char* bspr = smem + 98304;

  stage_all(bcur, 0);
  stage_all(bnxt, 1);
  asm volatile("s_waitcnt vmcnt(6)" ::: "memory");
  __builtin_amdgcn_s_barrier();

  for (int tt = 0; tt < NT; ++tt) {
    const bool pf2 = (tt + 2 < NT);
    bf16x8 af[4], af2[4], bfr[4], bfr2[4];

    auto LDA = [&](bf16x8* dst8, int KK) {
#pragma unroll
      for (int mf = 0; mf < 4; ++mf)
        dst8[mf] = *reinterpret_cast<const bf16x8*>(
            bcur + KK * 8192 + (wm * 64 + mf * 16 + l15) * 64 + swz16);
    };
    auto LDB = [&](bf16x8* dst8, int KK) {
#pragma unroll
      for (int nf = 0; nf < 4; ++nf)
        dst8[nf] = *reinterpret_cast<const bf16x8*>(
            bcur + 16384 + KK * 16384 + (wn * 64 + nf * 16 + l15) * 64 + swz16);
    };

    LDA(af, 0);
    LDB(bfr, 0);
    __builtin_amdgcn_sched_barrier(0);
    LDA(af2, 1);
    LDB(bfr2, 1);
    __builtin_amdgcn_sched_barrier(0);
    if (pf2) stage_all(bspr, tt + 2);
    asm volatile("s_waitcnt lgkmcnt(8)" ::: "memory");
    __builtin_amdgcn_sched_barrier(0);
    __builtin_amdgcn_s_setprio(1);
    MFMA_T(af, bfr, 0)
    asm volatile("s_waitcnt lgkmcnt(0)" ::: "memory");
    __builtin_amdgcn_sched_barrier(0);
    MFMA_T(af2, bfr2, 0)
    __builtin_amdgcn_s_setprio(0);
    if (pf2) {
      asm volatile("s_waitcnt vmcnt(6)" ::: "memory");
    } else {
      asm volatile("s_waitcnt vmcnt(0)" ::: "memory");
    }
    __builtin_amdgcn_s_barrier();

    char* tmp = bcur;
    bcur = bnxt;
    bnxt = bspr;
    bspr = tmp;
  }

  // ---- epilogue (cached stores) ----
  const int rb = brow0 + wm * 64;
  const int cb = bcol0 + wn * 64;
#pragma unroll
  for (int m = 0; m < 4; ++m) {
#pragma unroll
    for (int n = 0; n < 4; ++n) {
      const int c = cb + n * 16 + l15;
#pragma unroll
      for (int j = 0; j < 4; ++j) {
        const int r = rb + m * 16 + (lane >> 4) * 4 + j;
        float v = acc[m][n][j];
        if constexpr (EPI == EPIN_PROJ) {
          v += bias[c] + resid[(size_t)r * 1024 + c];
          out[(size_t)r * 1024 + c] = v;
        } else if constexpr (EPI == EPIN_FC2) {
          v += bias[c];
          out[(size_t)r * 1024 + c] = v;                                   // hidden_out
          out2_f[(size_t)r * 1024 + c] = resid[(size_t)r * 1024 + c] + v;  // final x
        } else {  // EPIN_QKV
          const int sec = c >> 10, cc = c & 1023;
          out[(size_t)sec * OUT_SEC + (size_t)r * 1024 + cc] = v;
          const size_t boff =
              (((size_t)(r >> 10) * 16 + (cc >> 6)) * 1024 + (r & 1023)) * 64 + (cc & 63);
          // Qb pre-scaled by 0.125 * log2(e) for exp2-based softmax
          if (sec == 0) h1[boff] = f2bf(v * 0.18033688f);
          else if (sec == 1) h2[boff] = f2bf(v);       // Kb
        }
      }
    }
  }
}

// =====================================================================
// attn v4 (unchanged): swapped-operand, QBLK=32/wave, 2-buffer LDS,
// single barrier + distance-1-tile vmcnt(0) per tile, cvt_pk + max3.
// =====================================================================
__global__ __launch_bounds__(256, 4) void attn_kernel(const u16* __restrict__ Qb,
                                                      const u16* __restrict__ Kb,
                                                      const u16* __restrict__ Vtb,
                                                      u16* __restrict__ ao) {
  const int orig = blockIdx.y * gridDim.x + blockIdx.x;  // 0..1023
  const int wid = (orig & 7) * 128 + (orig >> 3);
  const int bh = wid >> 3;
  const int qt = wid & 7;
  const int b = bh >> 4, h = bh & 15;
  const int t = threadIdx.x, lane = t & 63, wv = t >> 6;
  const int l15 = lane & 15, g = lane >> 4;

  __shared__ u16 KV[2][8192];   // per buffer: K [64][64] @0, V [64][64] @8KB (swizzled)

  const int q0 = qt * 128 + wv * 32;
  bf16x8 qfA[2], qfB[2];
#pragma unroll
  for (int c = 0; c < 2; ++c) {
    qfA[c] = *reinterpret_cast<const bf16x8*>(
        Qb + (size_t)bh * 65536 + (size_t)(q0 + l15) * 64 + c * 32 + g * 8);
    qfB[c] = *reinterpret_cast<const bf16x8*>(
        Qb + (size_t)bh * 65536 + (size_t)(q0 + 16 + l15) * 64 + c * 32 + g * 8);
  }

  f32x4 zero = {0.f, 0.f, 0.f, 0.f};
  f32x4 accO0[4], accO1[4];
#pragma unroll
  for (int nb = 0; nb < 4; ++nb) { accO0[nb] = zero; accO1[nb] = zero; }
  float m0 = -1e30f, m1 = -1e30f, lr0 = 0.f, lr1 = 0.f;

  const char* ktile0 = (const char*)(Kb + (size_t)bh * 65536);
  const char* vbase = (const char*)(Vtb + (size_t)bh * 65536);

  auto stage = [&](int buf, int kv0) {
    char* base = (char*)KV[buf];
#pragma unroll
    for (int i = 0; i < 2; ++i) {
      const int o = i * 4096 + t * 16;
      const int row = o >> 7, colb = o & 127;
      const int swz = colb ^ ((row & 7) << 4);
      gl_lds16(ktile0 + (size_t)kv0 * 128 + (size_t)row * 128 + swz, base + o);
      gl_lds16(vbase + (size_t)row * 2048 + (size_t)kv0 * 2 + swz, base + 8192 + o);
    }
  };  // 4 issues

  stage(0, 0);
  int cur = 0;

  const int a0 = (l15 + ((g & 1) << 5)) << 2;
  const int a1 = a0 + 64;
  const bool up = (lane & 32) != 0;

  for (int tile = 0; tile < 16; ++tile) {
    asm volatile("s_waitcnt vmcnt(0)" ::: "memory");
    __builtin_amdgcn_s_barrier();
    if (tile + 1 < 16) stage(cur ^ 1, (tile + 1) * 64);

    const char* kcur = (const char*)KV[cur];
    const char* vcur = kcur + 8192;

    f32x4 s0[4], s1[4];
#pragma unroll
    for (int jb = 0; jb < 4; ++jb) { s0[jb] = zero; s1[jb] = zero; }
#pragma unroll
    for (int jb = 0; jb < 4; ++jb)
#pragma unroll
      for (int c = 0; c < 2; ++c) {
        const int row = jb * 16 + l15;
        const int colb = c * 64 + g * 16;
        bf16x8 kf = *reinterpret_cast<const bf16x8*>(
            kcur + row * 128 + (colb ^ ((row & 7) << 4)));
        s0[jb] = __builtin_amdgcn_mfma_f32_16x16x32_bf16(kf, qfA[c], s0[jb], 0, 0, 0);
        s1[jb] = __builtin_amdgcn_mfma_f32_16x16x32_bf16(kf, qfB[c], s1[jb], 0, 0, 0);
      }

    int w0[4][2], w1[4][2];
    {
      float ta = max3f(s0[0][0], s0[0][1], s0[0][2]);
      float tb = max3f(s0[0][3], s0[1][0], s0[1][1]);
      float tc = max3f(s0[1][2], s0[1][3], s0[2][0]);
      float td = max3f(s0[2][1], s0[2][2], s0[2][3]);
      float te = max3f(s0[3][0], s0[3][1], s0[3][2]);
      float mt = max3f(max3f(ta, tb, tc), max3f(td, te, s0[3][3]), -1e30f);
      mt = fmaxf(mt, __shfl_xor(mt, 16, 64));
      mt = fmaxf(mt, __shfl_xor(mt, 32, 64));
      if (!__all(mt <= m0 + 8.0f)) {
        const float mn = fmaxf(m0, mt);
        const float sc = exp2f(m0 - mn);
        lr0 *= sc;
#pragma unroll
        for (int nb = 0; nb < 4; ++nb) accO0[nb] *= sc;
        m0 = mn;
      }
      float rs = 0.f;
#pragma unroll
      for (int jb = 0; jb < 4; ++jb)
#pragma unroll
        for (int r = 0; r < 4; ++r) {
          const float p = exp2f(s0[jb][r] - m0);
          s0[jb][r] = p;
          rs += p;
        }
      lr0 += rs;
#pragma unroll
      for (int jb = 0; jb < 4; ++jb) {
        w0[jb][0] = cvt_pk_bf16(s0[jb][0], s0[jb][1]);
        w0[jb][1] = cvt_pk_bf16(s0[jb][2], s0[jb][3]);
      }
    }
    {
      float ta = max3f(s1[0][0], s1[0][1], s1[0][2]);
      float tb = max3f(s1[0][3], s1[1][0], s1[1][1]);
      float tc = max3f(s1[1][2], s1[1][3], s1[2][0]);
      float td = max3f(s1[2][1], s1[2][2], s1[2][3]);
      float te = max3f(s1[3][0], s1[3][1], s1[3][2]);
      float mt = max3f(max3f(ta, tb, tc), max3f(td, te, s1[3][3]), -1e30f);
      mt = fmaxf(mt, __shfl_xor(mt, 16, 64));
      mt = fmaxf(mt, __shfl_xor(mt, 32, 64));
      if (!__all(mt <= m1 + 8.0f)) {
        const float mn = fmaxf(m1, mt);
        const float sc = exp2f(m1 - mn);
        lr1 *= sc;
#pragma unroll
        for (int nb = 0; nb < 4; ++nb) accO1[nb] *= sc;
        m1 = mn;
      }
      float rs = 0.f;
#pragma unroll
      for (int jb = 0; jb < 4; ++jb)
#pragma unroll
        for (int r = 0; r < 4; ++r) {
          const float p = exp2f(s1[jb][r] - m1);
          s1[jb][r] = p;
          rs += p;
        }
      lr1 += rs;
#pragma unroll
      for (int jb = 0; jb < 4; ++jb) {
        w1[jb][0] = cvt_pk_bf16(s1[jb][0], s1[jb][1]);
        w1[jb][1] = cvt_pk_bf16(s1[jb][2], s1[jb][3]);
      }
    }

#pragma unroll
    for (int c = 0; c < 2; ++c) {
      int p0w0 = __builtin_amdgcn_ds_bpermute(a0, w0[2 * c][0]);
      int p0w0h = __builtin_amdgcn_ds_bpermute(a0, w0[2 * c + 1][0]);
      int p0w1 = __builtin_amdgcn_ds_bpermute(a0, w0[2 * c][1]);
      int p0w1h = __builtin_amdgcn_ds_bpermute(a0, w0[2 * c + 1][1]);
      int p0w2 = __builtin_amdgcn_ds_bpermute(a1, w0[2 * c][0]);
      int p0w2h = __builtin_amdgcn_ds_bpermute(a1, w0[2 * c + 1][0]);
      int p0w3 = __builtin_amdgcn_ds_bpermute(a1, w0[2 * c][1]);
      int p0w3h = __builtin_amdgcn_ds_bpermute(a1, w0[2 * c + 1][1]);
      alignas(16) int word0[4] = {up ? p0w0h : p0w0, up ? p0w1h : p0w1,
                                  up ? p0w2h : p0w2, up ? p0w3h : p0w3};
      bf16x8 pf0 = *reinterpret_cast<bf16x8*>(word0);

      int p1w0 = __builtin_amdgcn_ds_bpermute(a0, w1[2 * c][0]);
      int p1w0h = __builtin_amdgcn_ds_bpermute(a0, w1[2 * c + 1][0]);
      int p1w1 = __builtin_amdgcn_ds_bpermute(a0, w1[2 * c][1]);
      int p1w1h = __builtin_amdgcn_ds_bpermute(a0, w1[2 * c + 1][1]);
      int p1w2 = __builtin_amdgcn_ds_bpermute(a1, w1[2 * c][0]);
      int p1w2h = __builtin_amdgcn_ds_bpermute(a1, w1[2 * c + 1][0]);
      int p1w3 = __builtin_amdgcn_ds_bpermute(a1, w1[2 * c][1]);
      int p1w3h = __builtin_amdgcn_ds_bpermute(a1, w1[2 * c + 1][1]);
      alignas(16) int word1[4] = {up ? p1w0h : p1w0, up ? p1w1h : p1w1,
                                  up ? p1w2h : p1w2, up ? p1w3h : p1w3};
      bf16x8 pf1 = *reinterpret_cast<bf16x8*>(word1);

#pragma unroll
      for (int nb = 0; nb < 4; ++nb) {
        const int row = nb * 16 + l15;
        const int colb = c * 64 + g * 16;
        bf16x8 vf = *reinterpret_cast<const bf16x8*>(
            vcur + row * 128 + (colb ^ ((row & 7) << 4)));
        accO0[nb] = __builtin_amdgcn_mfma_f32_16x16x32_bf16(vf, pf0, accO0[nb], 0, 0, 0);
        accO1[nb] = __builtin_amdgcn_mfma_f32_16x16x32_bf16(vf, pf1, accO1[nb], 0, 0, 0);
      }
    }

    cur ^= 1;
  }

  lr0 += __shfl_xor(lr0, 16, 64);
  lr0 += __shfl_xor(lr0, 32, 64);
  lr1 += __shfl_xor(lr1, 16, 64);
  lr1 += __shfl_xor(lr1, 32, 64);
  const float rl0 = __builtin_amdgcn_rcpf(lr0);
  const float rl1 = __builtin_amdgcn_rcpf(lr1);

  u16* dst0 = ao + (size_t)(b * 1024 + q0 + l15) * 1024 + h * 64 + g * 4;
  u16* dst1 = ao + (size_t)(b * 1024 + q0 + 16 + l15) * 1024 + h * 64 + g * 4;
#pragma unroll
  for (int nb = 0; nb < 4; ++nb) {
    alignas(8) u16 pk0[4], pk1[4];
#pragma unroll
    for (int j = 0; j < 4; ++j) {
      pk0[j] = f2bf(accO0[nb][j] * rl0);
      pk1[j] = f2bf(accO1[nb][j] * rl1);
    }
    *reinterpret_cast<uint2*>(dst0 + nb * 16) = *reinterpret_cast<uint2*>(pk0);
    *reinterpret_cast<uint2*>(dst1 + nb * 16) = *reinterpret_cast<uint2*>(pk1);
  }
}

// ---------------- launch ----------------
extern "C" void kernel_launch(void* const* d_in, const int* in_sizes, int n_in,
                              void* d_out, int out_size, void* d_ws, size_t ws_size,
                              hipStream_t stream) {
  const float* x      = (const float*)d_in[0];
  const float* n1w    = (const float*)d_in[1];
  const float* n1b    = (const float*)d_in[2];
  const float* qkv_w  = (const float*)d_in[3];
  const float* proj_w = (const float*)d_in[4];
  const float* proj_b = (const float*)d_in[5];
  const float* n2w    = (const float*)d_in[6];
  const float* n2b    = (const float*)d_in[7];
  const float* fc1_w  = (const float*)d_in[8];
  const float* fc1_b  = (const float*)d_in[9];
  const float* fc2_w  = (const float*)d_in[10];
  const float* fc2_b  = (const float*)d_in[11];
  float* out = (float*)d_out;

  // workspace layout (u16 elements)
  u16* wsb    = (u16*)d_ws;
  u16* w_qkv  = wsb;               // 3072*1024
  u16* w_proj = wsb + 3145728;     // 1024*1024
  u16* w_fc1  = wsb + 4194304;     // 4096*1024
  u16* w_fc2  = wsb + 8388608;     // 1024*4096
  u16* xn     = wsb + 12582912;    // 8192*1024 (reused for xn2)
  u16* Qb     = wsb + 20971520;    // 128*1024*64 bf16 (scaled q)
  u16* Kb     = wsb + 29360128;    // 128*1024*64
  u16* Vtw    = wsb + 37748736;    // 128*64*1024
  u16* ao     = wsb + 46137344;    // 8192*1024
  u16* hbuf   = wsb + 20971520;    // 8192*4096, aliases Qb..ao (dead by fc1)

  (void)hipFuncSetAttribute((const void*)gemm8<EPI8_FC1>,
                            hipFuncAttributeMaxDynamicSharedMemorySize, 131072);
  (void)hipFuncSetAttribute((const void*)gemm8n<EPIN_PROJ>,
                            hipFuncAttributeMaxDynamicSharedMemorySize, 147456);
  (void)hipFuncSetAttribute((const void*)gemm8n<EPIN_FC2>,
                            hipFuncAttributeMaxDynamicSharedMemorySize, 147456);
  (void)hipFuncSetAttribute((const void*)gemm8n<EPIN_QKV>,
                            hipFuncAttributeMaxDynamicSharedMemorySize, 147456);

  cvt_kernel<<<3072, 256, 0, stream>>>(qkv_w, w_qkv, 786432);
  cvt_kernel<<<1024, 256, 0, stream>>>(proj_w, w_proj, 262144);
  cvt_kernel<<<4096, 256, 0, stream>>>(fc1_w, w_fc1, 1048576);
  cvt_kernel<<<4096, 256, 0, stream>>>(fc2_w, w_fc2, 1048576);

  ln_kernel<<<TOK, 256, 0, stream>>>(x, n1w, n1b, xn);
  // q,k,v fp32 -> d_out sections 1..3 ; Qb/Kb bf16 (grid 64x12 = 768)
  gemm8n<EPIN_QKV><<<768, 512, 147456, stream>>>(
      xn, w_qkv, nullptr, nullptr, out + OUT_SEC, nullptr, Qb, Kb, 1024);
  vtrans_kernel<<<dim3(128, 16), 256, 0, stream>>>(out + 3 * (size_t)OUT_SEC, Vtw);
  attn_kernel<<<dim3(128, 8), 256, 0, stream>>>(Qb, Kb, Vtw, ao);
  // x_mid = x + ao*proj^T + proj_b (grid 64x4 = 256)
  gemm8n<EPIN_PROJ><<<256, 512, 147456, stream>>>(
      ao, w_proj, proj_b, x, out, nullptr, nullptr, nullptr, 1024);
  ln_kernel<<<TOK, 256, 0, stream>>>(out, n2w, n2b, xn);
  // h = gelu(xn2*fc1^T + fc1_b) (256^2 tile, grid 32x16 = 512)
  gemm8<EPI8_FC1><<<512, 512, 131072, stream>>>(
      xn, w_fc1, fc1_b, nullptr, hbuf, nullptr, 1024);
  // hidden + final x (grid 64x4 = 256)
  gemm8n<EPIN_FC2><<<256, 512, 147456, stream>>>(
      hbuf, w_fc2, fc2_b, out, out + 4 * (size_t)OUT_SEC, out, nullptr, nullptr, 4096);
}